// Round 1
// baseline (613.567 us; speedup 1.0000x reference)
//
#include <hip/hip_runtime.h>

// LNCC DEBUG1: num = (tp_sum - (p_sum/729)*t_sum)^2 + 1e-5, 9^3 box sums, SAME zero pad.
//
// R5: 3-deep software pipeline, ONE barrier per plane (was 2).
// Double-buffered rowT and pcol; per iteration j the three stages are independent:
//   A: rowsum(plane j+1)  regs -> rowT[(j+1)&1]
//   B: colsum(plane j)    rowT[j&1] -> pcol[j&1]      (rowT[j&1] sealed by prev barrier)
//   C: gather(plane j-1)  pcol[(j-1)&1] -> ring/out   (pcol sealed by prev barrier)
// so a single { s_waitcnt lgkmcnt(0); s_barrier } per iteration gives all cross-wave
// visibility. Critical path per plane: max(stages) + 1 barrier instead of sum + 2.
// Also: loop-invariant hoisting (quad x-masks, row base ptrs, a-source select),
// incremental z plane offset, SALU parity offsets for buffer select.
// __launch_bounds__(1024, 8) pins VGPR<=64 so 2 blocks (32 waves) stay resident per CU
// (LDS 58.5 KB/block x2 = 117 KB < 160 KB).

#define N 192
#define RSTRIDE 46                 // rowT row stride: 2-way banks (free) + 8B-aligned float2
#define RBUF (3 * 32 * RSTRIDE)    // 4416 floats per rowT buffer
#define PBUF (3 * 32 * 32)         // 3072 floats per pcol buffer

// LDS-only barrier: drain LDS ops, then barrier. No vmcnt drain (prefetch stays in flight).
#define LDS_BARRIER() asm volatile("s_waitcnt lgkmcnt(0)\n\ts_barrier" ::: "memory")

__global__ __launch_bounds__(1024, 8)
void lncc_kernel(const float* __restrict__ t_in,
                 const float* __restrict__ p_in,
                 float* __restrict__ out)
{
    __shared__ __align__(16) float rowT[2 * RBUF];   // 34.5 KB
    __shared__ __align__(16) float pcol[2 * PBUF];   // 24 KB

    // ---- work assignment: 512 blocks = 72 xy tiles x {8 or 7} z-chunks ----
    const int bid = blockIdx.x;
    int xy, Z, z0;
    if (bid < 64) {                 // tiles 0..7: 8 chunks of Z=24
        xy = bid >> 3;
        Z  = 24;
        z0 = (bid & 7) * 24;
    } else {                        // tiles 8..71: 7 chunks (28,28,28,27,27,27,27)
        const int q  = bid - 64;
        xy = 8 + q / 7;
        const int zi = q % 7;
        if (zi < 3) { Z = 28; z0 = zi * 28; }
        else        { Z = 27; z0 = 84 + (zi - 3) * 27; }
    }
    const int P = Z + 8;            // input plane count for this chunk

    const int b  = xy / 36;
    const int t6 = xy % 36;
    const int y0 = (t6 / 6) * 32, x0 = (t6 % 6) * 32;
    const int tid = threadIdx.x;

    // ---- L (row-sum) decode: 3 fields x 40 rows x 8 x-quads = 960 slots (15 waves)
    const int  lf   = tid / 320;          // 0=t 1=p 2=tp (wave-uniform)
    const int  ls   = tid - lf * 320;
    const int  lry  = ls >> 3;            // raw row 0..39
    const int  lxq  = ls & 7;             // x quad 0..7
    const int  lgy  = y0 - 4 + lry;
    const int  lgx0 = x0 - 4 + 4 * lxq;   // 16B-aligned quad base
    const bool lactive = (tid < 960);
    const bool lyok = ((unsigned)lgy < (unsigned)N);
    const bool lv   = lactive && lyok;
    // loop-invariant x validity per quad
    const bool q0ok = ((unsigned)lgx0 < (unsigned)N);
    const bool q1ok = ((unsigned)(lgx0 + 4) < (unsigned)N);
    const bool q2ok = ((unsigned)(lgx0 + 8) < (unsigned)N);

    // ---- C (col-sum) decode: 3 fields x 8 y-quads x 32 x = 768 slots (12 waves)
    const int  cf  = tid >> 8;
    const int  cyq = (tid >> 5) & 7;
    const int  cx  = tid & 31;
    const bool cactive = (tid < 768);

    // ---- G decode: thread owns output column (gx,gy)
    const int gx = tid & 31;
    const int gy = tid >> 5;

    const size_t plane = (size_t)N * N;
    const float* tb = t_in + (size_t)b * N * plane;
    const float* pb = p_in + (size_t)b * N * plane;
    float*       ob = out  + (size_t)b * N * plane
                           + (size_t)(y0 + gy) * N + (x0 + gx);

    // loop-invariant row base pointers (y clamped so addr math stays sane; loads guarded by lv)
    const int lgyc = lyok ? lgy : 0;
    const float* const trow = tb + (size_t)lgyc * N;
    const float* const prow = pb + (size_t)lgyc * N;
    const float* const arow = (lf == 1) ? prow : trow;   // a-source select hoisted

    // per-thread LDS base pointers (buffer 0; add parity*RBUF/PBUF at use — SALU uniform)
    float* const       wpA = &rowT[(lf * 32 + 4 * lxq) * RSTRIDE + lry];
    const float* const rbB = &rowT[(cf * 32 + cx) * RSTRIDE + 4 * cyq];
    float* const       pcB = &pcol[cf * 1024 + (4 * cyq) * 32 + cx];
    const float* const pgC = &pcol[gy * 32 + gx];

    float ring_t[9], ring_p[9], ring_tp[9];
    float sum_t = 0.f, sum_p = 0.f, sum_tp = 0.f;
    #pragma unroll
    for (int i = 0; i < 9; ++i) { ring_t[i] = 0.f; ring_p[i] = 0.f; ring_tp[i] = 0.f; }

    const float4 z4 = make_float4(0.f, 0.f, 0.f, 0.f);
    float4 cur0 = z4, cur1 = z4, cur2 = z4;     // row-sum-ready 12 floats for plane j+1
    float4 fa0, fa1, fa2, fc0, fc1, fc2;        // in-flight prefetch (plane j+2)

#define ISSUE_LOADS(ZOFS, COND) do { \
    fa0 = z4; fa1 = z4; fa2 = z4; fc0 = z4; fc1 = z4; fc2 = z4; \
    if (COND) { \
        const float* ar = arow + (ZOFS); \
        const float* cr = prow + (ZOFS); \
        if (q0ok) { fa0 = *(const float4*)(ar + lgx0);     if (lf == 2) fc0 = *(const float4*)(cr + lgx0); } \
        if (q1ok) { fa1 = *(const float4*)(ar + lgx0 + 4); if (lf == 2) fc1 = *(const float4*)(cr + lgx0 + 4); } \
        if (q2ok) { fa2 = *(const float4*)(ar + lgx0 + 8); if (lf == 2) fc2 = *(const float4*)(cr + lgx0 + 8); } \
    } } while (0)

#define FINALIZE() do { \
    if (lf == 2) { \
        fa0.x *= fc0.x; fa0.y *= fc0.y; fa0.z *= fc0.z; fa0.w *= fc0.w; \
        fa1.x *= fc1.x; fa1.y *= fc1.y; fa1.z *= fc1.z; fa1.w *= fc1.w; \
        fa2.x *= fc2.x; fa2.y *= fc2.y; fa2.z *= fc2.z; fa2.w *= fc2.w; \
    } \
    cur0 = fa0; cur1 = fa1; cur2 = fa2; } while (0)

#define ROWSUM_STORE(BOFS) do { if (lactive) { \
    const float v0 = cur0.x, v1 = cur0.y, v2  = cur0.z, v3  = cur0.w; \
    const float v4 = cur1.x, v5 = cur1.y, v6  = cur1.z, v7  = cur1.w; \
    const float v8 = cur2.x, v9 = cur2.y, v10 = cur2.z, v11 = cur2.w; \
    const float s0 = ((v0 + v1) + (v2 + v3)) + ((v4 + v5) + (v6 + v7)) + v8; \
    const float s1 = s0 - v0 + v9; \
    const float s2 = s1 - v1 + v10; \
    const float s3 = s2 - v2 + v11; \
    float* wp = wpA + (BOFS); \
    wp[0] = s0; wp[RSTRIDE] = s1; wp[2 * RSTRIDE] = s2; wp[3 * RSTRIDE] = s3; } } while (0)

#define COLSUM(ROFS, POFS) do { if (cactive) { \
    const float* rb = rbB + (ROFS); \
    const float2 u0 = *(const float2*)(rb + 0); \
    const float2 u1 = *(const float2*)(rb + 2); \
    const float2 u2 = *(const float2*)(rb + 4); \
    const float2 u3 = *(const float2*)(rb + 6); \
    const float2 u4 = *(const float2*)(rb + 8); \
    const float2 u5 = *(const float2*)(rb + 10); \
    const float w0 = u0.x, w1 = u0.y, w2  = u1.x, w3  = u1.y; \
    const float w4 = u2.x, w5 = u2.y, w6  = u3.x, w7  = u3.y; \
    const float w8 = u4.x, w9 = u4.y, w10 = u5.x, w11 = u5.y; \
    const float c0 = ((w0 + w1) + (w2 + w3)) + ((w4 + w5) + (w6 + w7)) + w8; \
    const float c1 = c0 - w0 + w9; \
    const float c2 = c1 - w1 + w10; \
    const float c3 = c2 - w2 + w11; \
    float* pc = pcB + (POFS); \
    pc[0] = c0; pc[32] = c1; pc[64] = c2; pc[96] = c3; } } while (0)

    // ---- prologue: cur <- plane 0; rowsum(0) -> rowT[0]; cur <- plane 1 ----
    ISSUE_LOADS((long)(z0 - 4) * (long)plane,
                ((unsigned)(z0 - 4) < (unsigned)N) && lv);
    FINALIZE();                         // cur = plane 0 (zeros if z OOB)
    ROWSUM_STORE(0);                    // rowsum(plane 0) -> rowT buffer 0
    ISSUE_LOADS((long)(z0 - 3) * (long)plane,
                ((unsigned)(z0 - 3) < (unsigned)N) && lv);
    FINALIZE();                         // cur = plane 1
    LDS_BARRIER();                      // seal rowT[0] for B at j=0

    long zoff = (long)(z0 - 2) * (long)plane;   // global z offset of plane j+2 at j=0

    #pragma unroll 1
    for (int k = 0; k < 5; ++k) {
      #pragma unroll
      for (int r = 0; r < 9; ++r) {
        const int j = k * 9 + r;
        if (j > P) break;               // block-uniform; barriers stay uniform

        // ---- 1. issue prefetch loads for plane j+2 (consumed at FINALIZE) ----
        ISSUE_LOADS(zoff,
                    (j + 2 < P) && ((unsigned)(z0 + j - 2) < (unsigned)N) && lv);

        // wave-uniform double-buffer offsets (SALU)
        const int pj    = j & 1;
        const int rofsA = (pj ^ 1) * RBUF;   // (j+1)&1
        const int rofsB = pj * RBUF;         // j&1
        const int pofsB = pj * PBUF;         // j&1
        const int pofsC = (pj ^ 1) * PBUF;   // (j-1)&1

        // ---- 2. A: rowsum(plane j+1) regs -> rowT[(j+1)&1] ----
        ROWSUM_STORE(rofsA);

        // ---- 3. B: colsum(plane j): rowT[j&1] -> pcol[j&1] ----
        COLSUM(rofsB, pofsB);

        // ---- 4. C: gather(plane j-1) from pcol[(j-1)&1], z-ring, output ----
        float Pt = 0.f, Pp = 0.f, Ptp = 0.f;
        if ((j >= 1) && ((unsigned)(z0 + j - 5) < (unsigned)N)) {   // plane j-1 valid
            const float* pg = pgC + pofsC;
            Pt  = pg[0];
            Pp  = pg[1024];
            Ptp = pg[2048];
        }
        {
            const int s = (r + 8) % 9;           // (j-1) mod 9, static per unrolled r
            sum_t  += Pt  - ring_t[s];  ring_t[s]  = Pt;
            sum_p  += Pp  - ring_p[s];  ring_p[s]  = Pp;
            sum_tp += Ptp - ring_tp[s]; ring_tp[s] = Ptp;
        }
        if (j >= 9) {                            // i=j-1 in [8, P) given loop bound
            const float cross = sum_tp - (sum_p * (1.0f / 729.0f)) * sum_t;
            ob[(size_t)(z0 + j - 9) * plane] = cross * cross + 1e-5f;
        }

        // ---- 5. finalize: cur <- plane j+2 (loads have landed under A/B/C) ----
        FINALIZE();
        zoff += (long)plane;

        LDS_BARRIER();                  // one barrier per plane seals A/B writes
      }
    }

#undef ISSUE_LOADS
#undef FINALIZE
#undef ROWSUM_STORE
#undef COLSUM
}

extern "C" void kernel_launch(void* const* d_in, const int* in_sizes, int n_in,
                              void* d_out, int out_size, void* d_ws, size_t ws_size,
                              hipStream_t stream) {
    const float* y_true = (const float*)d_in[0];
    const float* y_pred = (const float*)d_in[1];
    float* out = (float*)d_out;
    dim3 grid(512);
    dim3 block(1024);
    hipLaunchKernelGGL(lncc_kernel, grid, block, 0, stream, y_true, y_pred, out);
}

// Round 2
// 223.751 us; speedup vs baseline: 2.7422x; 2.7422x over previous
//
#include <hip/hip_runtime.h>

// LNCC DEBUG1: num = (tp_sum - (p_sum/729)*t_sum)^2 + 1e-5, 9^3 box sums, SAME zero pad.
//
// R6 = R5 pipeline with the launch bound reverted to the R3-proven (1024, 4).
// R5's __launch_bounds__(1024, 8) made the backend allocate only 32 arch VGPRs
// (unified-file split), spilling ~34 live floats to scratch: WRITE_SIZE 55MB->1.0GB,
// FETCH 200MB->865MB, dur 112->530us. The pipeline itself worked (occupancy 41->82%).
//
// Pipeline (unchanged from R5): 3-deep, ONE lgkm barrier per plane.
// Double-buffered rowT and pcol; per iteration j the three stages are independent:
//   A: rowsum(plane j+1)  regs -> rowT[(j+1)&1]
//   B: colsum(plane j)    rowT[j&1] -> pcol[j&1]      (sealed by prev barrier)
//   C: gather(plane j-1)  pcol[(j-1)&1] -> ring/out   (sealed by prev barrier)
// Global prefetch of plane j+2 is register-destined and stays in flight across the
// whole iteration (LDS_BARRIER drains lgkmcnt only, not vmcnt).

#define N 192
#define RSTRIDE 46                 // rowT row stride: 2-way banks (free) + 8B-aligned float2
#define RBUF (3 * 32 * RSTRIDE)    // 4416 floats per rowT buffer
#define PBUF (3 * 32 * 32)         // 3072 floats per pcol buffer

// LDS-only barrier: drain LDS ops, then barrier. No vmcnt drain (prefetch stays in flight).
#define LDS_BARRIER() asm volatile("s_waitcnt lgkmcnt(0)\n\ts_barrier" ::: "memory")

__global__ __launch_bounds__(1024, 4)
void lncc_kernel(const float* __restrict__ t_in,
                 const float* __restrict__ p_in,
                 float* __restrict__ out)
{
    __shared__ __align__(16) float rowT[2 * RBUF];   // 34.5 KB
    __shared__ __align__(16) float pcol[2 * PBUF];   // 24 KB

    // ---- work assignment: 512 blocks = 72 xy tiles x {8 or 7} z-chunks ----
    const int bid = blockIdx.x;
    int xy, Z, z0;
    if (bid < 64) {                 // tiles 0..7: 8 chunks of Z=24
        xy = bid >> 3;
        Z  = 24;
        z0 = (bid & 7) * 24;
    } else {                        // tiles 8..71: 7 chunks (28,28,28,27,27,27,27)
        const int q  = bid - 64;
        xy = 8 + q / 7;
        const int zi = q % 7;
        if (zi < 3) { Z = 28; z0 = zi * 28; }
        else        { Z = 27; z0 = 84 + (zi - 3) * 27; }
    }
    const int P = Z + 8;            // input plane count for this chunk

    const int b  = xy / 36;
    const int t6 = xy % 36;
    const int y0 = (t6 / 6) * 32, x0 = (t6 % 6) * 32;
    const int tid = threadIdx.x;

    // ---- L (row-sum) decode: 3 fields x 40 rows x 8 x-quads = 960 slots (15 waves)
    const int  lf   = tid / 320;          // 0=t 1=p 2=tp (wave-uniform)
    const int  ls   = tid - lf * 320;
    const int  lry  = ls >> 3;            // raw row 0..39
    const int  lxq  = ls & 7;             // x quad 0..7
    const int  lgy  = y0 - 4 + lry;
    const int  lgx0 = x0 - 4 + 4 * lxq;   // 16B-aligned quad base
    const bool lactive = (tid < 960);
    const bool lyok = ((unsigned)lgy < (unsigned)N);
    const bool lv   = lactive && lyok;
    // loop-invariant x validity per quad
    const bool q0ok = ((unsigned)lgx0 < (unsigned)N);
    const bool q1ok = ((unsigned)(lgx0 + 4) < (unsigned)N);
    const bool q2ok = ((unsigned)(lgx0 + 8) < (unsigned)N);

    // ---- C (col-sum) decode: 3 fields x 8 y-quads x 32 x = 768 slots (12 waves)
    const int  cf  = tid >> 8;
    const int  cyq = (tid >> 5) & 7;
    const int  cx  = tid & 31;
    const bool cactive = (tid < 768);

    // ---- G decode: thread owns output column (gx,gy)
    const int gx = tid & 31;
    const int gy = tid >> 5;

    const size_t plane = (size_t)N * N;
    const float* tb = t_in + (size_t)b * N * plane;
    const float* pb = p_in + (size_t)b * N * plane;
    float*       ob = out  + (size_t)b * N * plane
                           + (size_t)(y0 + gy) * N + (x0 + gx);

    // loop-invariant row base pointers (y clamped so addr math stays sane; loads guarded by lv)
    const int lgyc = lyok ? lgy : 0;
    const float* const trow = tb + (size_t)lgyc * N;
    const float* const prow = pb + (size_t)lgyc * N;
    const float* const arow = (lf == 1) ? prow : trow;   // a-source select hoisted

    // per-thread LDS base pointers (buffer 0; add parity*RBUF/PBUF at use — SALU uniform)
    float* const       wpA = &rowT[(lf * 32 + 4 * lxq) * RSTRIDE + lry];
    const float* const rbB = &rowT[(cf * 32 + cx) * RSTRIDE + 4 * cyq];
    float* const       pcB = &pcol[cf * 1024 + (4 * cyq) * 32 + cx];
    const float* const pgC = &pcol[gy * 32 + gx];

    float ring_t[9], ring_p[9], ring_tp[9];
    float sum_t = 0.f, sum_p = 0.f, sum_tp = 0.f;
    #pragma unroll
    for (int i = 0; i < 9; ++i) { ring_t[i] = 0.f; ring_p[i] = 0.f; ring_tp[i] = 0.f; }

    const float4 z4 = make_float4(0.f, 0.f, 0.f, 0.f);
    float4 cur0 = z4, cur1 = z4, cur2 = z4;     // row-sum-ready 12 floats for plane j+1
    float4 fa0, fa1, fa2, fc0, fc1, fc2;        // in-flight prefetch (plane j+2)

#define ISSUE_LOADS(ZOFS, COND) do { \
    fa0 = z4; fa1 = z4; fa2 = z4; fc0 = z4; fc1 = z4; fc2 = z4; \
    if (COND) { \
        const float* ar = arow + (ZOFS); \
        const float* cr = prow + (ZOFS); \
        if (q0ok) { fa0 = *(const float4*)(ar + lgx0);     if (lf == 2) fc0 = *(const float4*)(cr + lgx0); } \
        if (q1ok) { fa1 = *(const float4*)(ar + lgx0 + 4); if (lf == 2) fc1 = *(const float4*)(cr + lgx0 + 4); } \
        if (q2ok) { fa2 = *(const float4*)(ar + lgx0 + 8); if (lf == 2) fc2 = *(const float4*)(cr + lgx0 + 8); } \
    } } while (0)

#define FINALIZE() do { \
    if (lf == 2) { \
        fa0.x *= fc0.x; fa0.y *= fc0.y; fa0.z *= fc0.z; fa0.w *= fc0.w; \
        fa1.x *= fc1.x; fa1.y *= fc1.y; fa1.z *= fc1.z; fa1.w *= fc1.w; \
        fa2.x *= fc2.x; fa2.y *= fc2.y; fa2.z *= fc2.z; fa2.w *= fc2.w; \
    } \
    cur0 = fa0; cur1 = fa1; cur2 = fa2; } while (0)

#define ROWSUM_STORE(BOFS) do { if (lactive) { \
    const float v0 = cur0.x, v1 = cur0.y, v2  = cur0.z, v3  = cur0.w; \
    const float v4 = cur1.x, v5 = cur1.y, v6  = cur1.z, v7  = cur1.w; \
    const float v8 = cur2.x, v9 = cur2.y, v10 = cur2.z, v11 = cur2.w; \
    const float s0 = ((v0 + v1) + (v2 + v3)) + ((v4 + v5) + (v6 + v7)) + v8; \
    const float s1 = s0 - v0 + v9; \
    const float s2 = s1 - v1 + v10; \
    const float s3 = s2 - v2 + v11; \
    float* wp = wpA + (BOFS); \
    wp[0] = s0; wp[RSTRIDE] = s1; wp[2 * RSTRIDE] = s2; wp[3 * RSTRIDE] = s3; } } while (0)

#define COLSUM(ROFS, POFS) do { if (cactive) { \
    const float* rb = rbB + (ROFS); \
    const float2 u0 = *(const float2*)(rb + 0); \
    const float2 u1 = *(const float2*)(rb + 2); \
    const float2 u2 = *(const float2*)(rb + 4); \
    const float2 u3 = *(const float2*)(rb + 6); \
    const float2 u4 = *(const float2*)(rb + 8); \
    const float2 u5 = *(const float2*)(rb + 10); \
    const float w0 = u0.x, w1 = u0.y, w2  = u1.x, w3  = u1.y; \
    const float w4 = u2.x, w5 = u2.y, w6  = u3.x, w7  = u3.y; \
    const float w8 = u4.x, w9 = u4.y, w10 = u5.x, w11 = u5.y; \
    const float c0 = ((w0 + w1) + (w2 + w3)) + ((w4 + w5) + (w6 + w7)) + w8; \
    const float c1 = c0 - w0 + w9; \
    const float c2 = c1 - w1 + w10; \
    const float c3 = c2 - w2 + w11; \
    float* pc = pcB + (POFS); \
    pc[0] = c0; pc[32] = c1; pc[64] = c2; pc[96] = c3; } } while (0)

    // ---- prologue: cur <- plane 0; rowsum(0) -> rowT[0]; cur <- plane 1 ----
    ISSUE_LOADS((long)(z0 - 4) * (long)plane,
                ((unsigned)(z0 - 4) < (unsigned)N) && lv);
    FINALIZE();                         // cur = plane 0 (zeros if z OOB)
    ROWSUM_STORE(0);                    // rowsum(plane 0) -> rowT buffer 0
    ISSUE_LOADS((long)(z0 - 3) * (long)plane,
                ((unsigned)(z0 - 3) < (unsigned)N) && lv);
    FINALIZE();                         // cur = plane 1
    LDS_BARRIER();                      // seal rowT[0] for B at j=0

    long zoff = (long)(z0 - 2) * (long)plane;   // global z offset of plane j+2 at j=0

    #pragma unroll 1
    for (int k = 0; k < 5; ++k) {
      #pragma unroll
      for (int r = 0; r < 9; ++r) {
        const int j = k * 9 + r;
        if (j > P) break;               // block-uniform; barriers stay uniform

        // ---- 1. issue prefetch loads for plane j+2 (consumed at FINALIZE) ----
        ISSUE_LOADS(zoff,
                    (j + 2 < P) && ((unsigned)(z0 + j - 2) < (unsigned)N) && lv);

        // wave-uniform double-buffer offsets (SALU)
        const int pj    = j & 1;
        const int rofsA = (pj ^ 1) * RBUF;   // (j+1)&1
        const int rofsB = pj * RBUF;         // j&1
        const int pofsB = pj * PBUF;         // j&1
        const int pofsC = (pj ^ 1) * PBUF;   // (j-1)&1

        // ---- 2. A: rowsum(plane j+1) regs -> rowT[(j+1)&1] ----
        ROWSUM_STORE(rofsA);

        // ---- 3. B: colsum(plane j): rowT[j&1] -> pcol[j&1] ----
        COLSUM(rofsB, pofsB);

        // ---- 4. C: gather(plane j-1) from pcol[(j-1)&1], z-ring, output ----
        float Pt = 0.f, Pp = 0.f, Ptp = 0.f;
        if ((j >= 1) && ((unsigned)(z0 + j - 5) < (unsigned)N)) {   // plane j-1 valid
            const float* pg = pgC + pofsC;
            Pt  = pg[0];
            Pp  = pg[1024];
            Ptp = pg[2048];
        }
        {
            const int s = (r + 8) % 9;           // (j-1) mod 9, static per unrolled r
            sum_t  += Pt  - ring_t[s];  ring_t[s]  = Pt;
            sum_p  += Pp  - ring_p[s];  ring_p[s]  = Pp;
            sum_tp += Ptp - ring_tp[s]; ring_tp[s] = Ptp;
        }
        if (j >= 9) {                            // i=j-1 in [8, P) given loop bound
            const float cross = sum_tp - (sum_p * (1.0f / 729.0f)) * sum_t;
            ob[(size_t)(z0 + j - 9) * plane] = cross * cross + 1e-5f;
        }

        // ---- 5. finalize: cur <- plane j+2 (loads have landed under A/B/C) ----
        FINALIZE();
        zoff += (long)plane;

        LDS_BARRIER();                  // one barrier per plane seals A/B writes
      }
    }

#undef ISSUE_LOADS
#undef FINALIZE
#undef ROWSUM_STORE
#undef COLSUM
}

extern "C" void kernel_launch(void* const* d_in, const int* in_sizes, int n_in,
                              void* d_out, int out_size, void* d_ws, size_t ws_size,
                              hipStream_t stream) {
    const float* y_true = (const float*)d_in[0];
    const float* y_pred = (const float*)d_in[1];
    float* out = (float*)d_out;
    dim3 grid(512);
    dim3 block(1024);
    hipLaunchKernelGGL(lncc_kernel, grid, block, 0, stream, y_true, y_pred, out);
}